// Round 4
// baseline (671.860 us; speedup 1.0000x reference)
//
#include <hip/hip_runtime.h>
#include <hip/hip_bf16.h>

typedef __hip_bfloat16 bf16;
typedef __attribute__((ext_vector_type(8))) short bfrag;   // 8 bf16 = 4 VGPRs
typedef __attribute__((ext_vector_type(4))) float ffrag;   // 4 fp32 acc

#define CDIM 128
#define TDIMC 64
#define MSGD 64
#define INV2PI 0.15915494309189535f

__device__ __forceinline__ unsigned short f2bf(float f) {
    union { __hip_bfloat16 h; unsigned short u; } cv;
    cv.h = __float2bfloat16(f);
    return cv.u;
}

// fast cos for pre-scaled (revolutions) argument: cos(2*pi*x)
__device__ __forceinline__ float fcos_rev(float xr) {
    float fr, c;
    asm("v_fract_f32 %0, %1" : "=v"(fr) : "v"(xr));   // [0,1) — v_cos takes revolutions
    asm("v_cos_f32 %0, %1" : "=v"(c) : "v"(xr < 0.f ? fr : fr));
    return c;
}

// wave-local LDS ordering point: drains this wave's ds ops, blocks compiler motion.
// Wave lockstep + lgkmcnt(0) is sufficient for cross-LANE (same-wave) LDS dependencies;
// the memory clobber + sched_barrier stop the compiler from hoisting lane-disjoint
// ds_reads above other lanes' writes (rule #18 / round-4 absmax bug pattern).
__device__ __forceinline__ void wave_lds_fence() {
    asm volatile("s_waitcnt lgkmcnt(0)" ::: "memory");
    __builtin_amdgcn_sched_barrier(0);
}

// ---------------- edge_index dtype detection ----------------
__global__ void detect_kernel(const int* __restrict__ ei, int samp, int* __restrict__ flag) {
    int i = blockIdx.x * blockDim.x + threadIdx.x;
    if (i < samp) {
        if (ei[2 * i + 1] != 0) atomicOr(flag, 1);   // int32 data -> odd words are dst values
    }
}

// ---------------- dst histogram straight from ei ----------------
__global__ void hist_kernel(const int* __restrict__ ei, int E, const int* __restrict__ flag,
                            int* __restrict__ count) {
    int e = blockIdx.x * 256 + threadIdx.x;
    if (e >= E) return;
    int is32 = *flag;
    int d = is32 ? ei[E + e] : ei[2 * (E + e)];   // int64 path: low word
    atomicAdd(&count[d], 1);
}

// ---------------- parallel scan: block-local pass ----------------
__global__ __launch_bounds__(1024)
void scan1_kernel(const int* __restrict__ count, int N,
                  int* __restrict__ cur, int* __restrict__ bsum) {
    __shared__ int wsum[16];
    __shared__ int woff[16];
    int t = threadIdx.x;
    int lane = t & 63, wv = t >> 6;
    int i = blockIdx.x * 1024 + t;
    int v = (i < N) ? count[i] : 0;
    int incl = v;
#pragma unroll
    for (int off = 1; off < 64; off <<= 1) {
        int n = __shfl_up(incl, off, 64);
        if (lane >= off) incl += n;
    }
    if (lane == 63) wsum[wv] = incl;
    __syncthreads();
    if (wv == 0) {
        int ws = (lane < 16) ? wsum[lane] : 0;
        int wi = ws;
#pragma unroll
        for (int off = 1; off < 16; off <<= 1) {
            int n = __shfl_up(wi, off, 64);
            if (lane >= off) wi += n;
        }
        if (lane < 16) woff[lane] = wi - ws;   // exclusive wave offset
        if (lane == 15) bsum[blockIdx.x] = wi; // block total
    }
    __syncthreads();
    if (i < N) cur[i] = woff[wv] + incl - v;
}

// ---------------- parallel scan: scan the block totals ----------------
__global__ void scan2_kernel(int* __restrict__ bsum, int nb) {
    int lane = threadIdx.x;   // launched with 64 threads
    int carry = 0;
    for (int base = 0; base < nb; base += 64) {
        int i = base + lane;
        int v = (i < nb) ? bsum[i] : 0;
        int incl = v;
#pragma unroll
        for (int off = 1; off < 64; off <<= 1) {
            int n = __shfl_up(incl, off, 64);
            if (lane >= off) incl += n;
        }
        if (i < nb) bsum[i] = carry + incl - v;   // exclusive
        carry += __shfl(incl, 63, 64);
    }
}

// ---------------- scatter into dst-sorted order (packed int4 rows) ----------------
__global__ void scatter_kernel(const int* __restrict__ ei, int E, const int* __restrict__ flag,
                               const int* __restrict__ tarr, const int* __restrict__ last_update,
                               int* __restrict__ cur, const int* __restrict__ bsum,
                               int4* __restrict__ ed_s) {
    int e = blockIdx.x * 256 + threadIdx.x;
    if (e >= E) return;
    int is32 = *flag;
    int s = is32 ? ei[e] : ei[2 * e];
    int d = is32 ? ei[E + e] : ei[2 * (E + e)];
    int pos = atomicAdd(&cur[d], 1) + bsum[d >> 10];
    float rt = (float)(last_update[s] - tarr[e]);
    ed_s[pos] = make_int4(s, d, e, __float_as_int(rt));
}

// ---------------- weight pre-transpose + bf16 convert ----------------
__global__ void wconv_kernel(const float* __restrict__ Wq, const float* __restrict__ Wk,
                             const float* __restrict__ Wv, const float* __restrict__ Ws,
                             const float* __restrict__ We,
                             short* __restrict__ Wt, short* __restrict__ Wet) {
    int idx = blockIdx.x * 256 + threadIdx.x;
    if (idx >= 5 * 16384) return;
    int mat = idx >> 14;
    int r = idx & 16383;
    int n = r >> 7, kk = r & 127;
    const float* W = (mat == 0) ? Wq : (mat == 1) ? Wk : (mat == 2) ? Wv : (mat == 3) ? Ws : We;
    short bv = (short)f2bf(W[kk * 128 + n]);
    if (mat < 4) Wt[(size_t)mat * 16384 + n * 128 + kk] = bv;
    else         Wet[n * 128 + kk] = bv;
}

// ---------------- MFMA node projections: wave w -> {q(f32), k(bf16), v(bf16), skip(f32)->out}
__global__ __launch_bounds__(256)
void proj_kernel(const float* __restrict__ x, const short* __restrict__ Wt,
                 const float* __restrict__ bq, const float* __restrict__ bk,
                 const float* __restrict__ bv, const float* __restrict__ bs,
                 float* __restrict__ q, short* __restrict__ kbf, short* __restrict__ vbf,
                 float* __restrict__ out, int N) {
    __shared__ __attribute__((aligned(16))) short sx[64][136];
    int tid = threadIdx.x;
    int n0 = blockIdx.x * 64;
    const float4* x4 = (const float4*)x;
    for (int i = tid; i < 64 * 32; i += 256) {
        int nl = i >> 5, c4 = i & 31;
        int n = n0 + nl;
        float4 f = (n < N) ? x4[(size_t)n * 32 + c4] : make_float4(0.f, 0.f, 0.f, 0.f);
        unsigned int lo = ((unsigned int)f2bf(f.y) << 16) | f2bf(f.x);
        unsigned int hi = ((unsigned int)f2bf(f.w) << 16) | f2bf(f.z);
        *(uint2*)&sx[nl][c4 * 4] = make_uint2(lo, hi);
    }
    __syncthreads();

    int lane = tid & 63, wv = tid >> 6;
    int n15 = lane & 15, quad = lane >> 4;
    const short* W = Wt + (size_t)wv * 16384;
    const float* bias = (wv == 0) ? bq : (wv == 1) ? bk : (wv == 2) ? bv : bs;

    ffrag acc[4][8];
#pragma unroll
    for (int r = 0; r < 4; ++r)
#pragma unroll
        for (int c = 0; c < 8; ++c)
            acc[r][c] = (ffrag){0.f, 0.f, 0.f, 0.f};

#pragma unroll
    for (int kc = 0; kc < 4; ++kc) {
        int kk = kc * 32 + quad * 8;
        bfrag a[4];
#pragma unroll
        for (int r = 0; r < 4; ++r)
            a[r] = *(const bfrag*)&sx[r * 16 + n15][kk];
#pragma unroll
        for (int c = 0; c < 8; ++c) {
            bfrag b = *(const bfrag*)&W[(c * 16 + n15) * 128 + kk];
#pragma unroll
            for (int r = 0; r < 4; ++r)
                acc[r][c] = __builtin_amdgcn_mfma_f32_16x16x32_bf16(a[r], b, acc[r][c], 0, 0, 0);
        }
    }

    if (wv == 1 || wv == 2) {          // k, v -> bf16 (halves edge-gather bytes)
        short* dsts = (wv == 1) ? kbf : vbf;
#pragma unroll
        for (int c = 0; c < 8; ++c) {
            int col = c * 16 + n15;
            float bval = bias[col];
#pragma unroll
            for (int r = 0; r < 4; ++r) {
#pragma unroll
                for (int g = 0; g < 4; ++g) {
                    int n = n0 + r * 16 + quad * 4 + g;
                    if (n < N) dsts[(size_t)n * CDIM + col] = (short)f2bf(acc[r][c][g] + bval);
                }
            }
        }
    } else {                           // q, skip -> f32
        float* dstp = (wv == 0) ? q : out;
#pragma unroll
        for (int c = 0; c < 8; ++c) {
            int col = c * 16 + n15;
            float bval = bias[col];
#pragma unroll
            for (int r = 0; r < 4; ++r) {
#pragma unroll
                for (int g = 0; g < 4; ++g) {
                    int n = n0 + r * 16 + quad * 4 + g;
                    if (n < N) dstp[(size_t)n * CDIM + col] = acc[r][c][g] + bval;
                }
            }
        }
    }
}

// ---------------- MFMA edge kernel: BARRIER-FREE per-wave pipeline ----------------
// Block = 256 threads = 4 fully independent waves; each wave owns 16 dst-sorted edges
// and rows [wv*16, wv*16+16) of sbuf. ALL LDS dependencies (meta, staging, A-frags,
// e-overlay, phase-3 e-reads) are wave-local -> no __syncthreads/s_barrier anywhere.
// Ordering at the 3 LDS handoff points is wave_lds_fence() (lockstep + lgkmcnt(0)).
// Waves stall independently on gathers -> real latency overlap (vs barrier coupling).
#define LOADQ(KA, QA, VA, JB) do {                                              \
    _Pragma("unroll")                                                           \
    for (int u = 0; u < 4; ++u) {                                               \
        int el = wv * 16 + (JB) * 4 + u;                                        \
        int s = s_src[el], d = s_dst[el];                                       \
        KA[u] = *(const unsigned int*)&k[(size_t)s * CDIM + 2 * lane];          \
        QA[u] = *(const float2*)&q[(size_t)d * CDIM + 2 * lane];                \
        VA[u] = *(const unsigned int*)&v[(size_t)s * CDIM + 2 * lane];          \
    } } while (0)

#define PROC(KA, QA, VA, JB) do {                                               \
    _Pragma("unroll")                                                           \
    for (int u = 0; u < 4; ++u) {                                               \
        int el = wv * 16 + (JB) * 4 + u;                                        \
        unsigned int ep = *(const unsigned int*)&sbuf[el][2 * lane];            \
        float ex0 = __uint_as_float(ep << 16);                                  \
        float ex1 = __uint_as_float(ep & 0xffff0000u);                          \
        float kx = __uint_as_float(KA[u] << 16) + ex0;                          \
        float ky = __uint_as_float(KA[u] & 0xffff0000u) + ex1;                  \
        float p = QA[u].x * kx + QA[u].y * ky;                                  \
        _Pragma("unroll")                                                       \
        for (int off = 1; off < 32; off <<= 1) p += __shfl_xor(p, off, 32);     \
        float exv = (e0 + el < E) ? __expf(p * 0.125f) : 0.f;                   \
        int d = s_dst[el];                                                      \
        if (d != cur_d) {   /* uniform across wave */                           \
            float* np = &num[(size_t)cur_d * CDIM + 2 * lane];                  \
            unsafeAtomicAdd(np, accx);                                          \
            unsafeAtomicAdd(np + 1, accy);                                      \
            if ((lane & 31) == 0) unsafeAtomicAdd(&den[cur_d * 2 + h], dacc);   \
            accx = 0.f; accy = 0.f; dacc = 0.f;                                 \
            cur_d = d;                                                          \
        }                                                                       \
        float vx = __uint_as_float(VA[u] << 16) + ex0;                          \
        float vy = __uint_as_float(VA[u] & 0xffff0000u) + ex1;                  \
        accx = fmaf(vx, exv, accx);                                             \
        accy = fmaf(vy, exv, accy);                                             \
        dacc += exv;                                                            \
    } } while (0)

__global__ __launch_bounds__(256)
void edge_kernel(const int4* __restrict__ ed_s,
                 const float* __restrict__ msg,
                 const float* __restrict__ time_w, const float* __restrict__ time_b,
                 const short* __restrict__ Wet,
                 const float* __restrict__ q, const short* __restrict__ k, const short* __restrict__ v,
                 float* __restrict__ num, float* __restrict__ den,
                 int E) {
    __shared__ __attribute__((aligned(16))) short sbuf[64][136];
    __shared__ int s_src[64], s_dst[64], s_perm[64];
    __shared__ float s_relt[64];
    int tid = threadIdx.x;
    int lane = tid & 63;
    int wv = tid >> 6;            // wave -> edges wv*16 .. wv*16+15, rows wv*16..+15

    // Bijective XCD-aware swizzle: each XCD owns a contiguous chunk of dst-sorted edges.
    int nwg = gridDim.x;
    int q8 = nwg >> 3, r8 = nwg & 7;
    int xcd = blockIdx.x & 7, idx8 = blockIdx.x >> 3;
    int bid = (xcd < r8 ? xcd * (q8 + 1) : r8 * (q8 + 1) + (xcd - r8) * q8) + idx8;
    int e0 = bid * 64;

    // --- wave-local meta load (lanes 0-15). ed_s has a zeroed 64-entry tail. ---
    if (lane < 16) {
        int4 ed = ed_s[e0 + wv * 16 + lane];
        s_src[wv * 16 + lane] = ed.x;
        s_dst[wv * 16 + lane] = ed.y;
        s_perm[wv * 16 + lane] = ed.z;
        s_relt[wv * 16 + lane] = __int_as_float(ed.w);
    }
    wave_lds_fence();   // meta writes -> all-lane reads (within wave)

    // Prefetch phase-3 batches 0,1 — latency hides under staging + MFMA, and no
    // barrier/vmcnt drain anywhere before their first use in PROC.
    unsigned int k0[4], v0[4], k1[4], v1[4], k2[4], v2[4], k3[4], v3[4];
    float2 q0[4], q1[4], q2[4], q3[4];
    LOADQ(k0, q0, v0, 0);
    LOADQ(k1, q1, v1, 1);

    // --- wave-local staging of this wave's 16 edge_attr rows ---
    {   // msg half first (issue global loads early), cos computed while in flight
        const float4* msg4 = (const float4*)msg;
        float4 m[4];
        int jel[4], jf4[4];
#pragma unroll
        for (int jj = 0; jj < 4; ++jj) {
            int j = jj * 64 + lane;            // 256 items: 16 edges x 16 float4
            jel[jj] = wv * 16 + (j >> 4);
            jf4[jj] = j & 15;
            m[jj] = msg4[(size_t)s_perm[jel[jj]] * 16 + jf4[jj]];
        }
        // cos half: 512 items = 16 edges x 32 pairs, 8 per lane
#pragma unroll
        for (int ii = 0; ii < 8; ++ii) {
            int i = ii * 64 + lane;
            int el = wv * 16 + (i >> 5), c2 = i & 31;
            float rt = s_relt[el];
            float2 w = ((const float2*)time_w)[c2];
            float2 b = ((const float2*)time_b)[c2];
            float c0 = fcos_rev(fmaf(rt, w.x * INV2PI, b.x * INV2PI));
            float c1 = fcos_rev(fmaf(rt, w.y * INV2PI, b.y * INV2PI));
            unsigned int pk = ((unsigned int)f2bf(c1) << 16) | f2bf(c0);
            *(unsigned int*)&sbuf[el][c2 * 2] = pk;
        }
#pragma unroll
        for (int jj = 0; jj < 4; ++jj) {
            unsigned int lo = ((unsigned int)f2bf(m[jj].y) << 16) | f2bf(m[jj].x);
            unsigned int hi = ((unsigned int)f2bf(m[jj].w) << 16) | f2bf(m[jj].z);
            *(uint2*)&sbuf[jel[jj]][TDIMC + jf4[jj] * 4] = make_uint2(lo, hi);
        }
    }
    wave_lds_fence();   // staging writes -> A-frag reads (within wave)

    int n15 = lane & 15, quad = lane >> 4;

    ffrag acc[8];
#pragma unroll
    for (int c = 0; c < 8; ++c) acc[c] = (ffrag){0.f, 0.f, 0.f, 0.f};
    __builtin_amdgcn_s_setprio(1);
#pragma unroll
    for (int kc = 0; kc < 4; ++kc) {
        int kk = kc * 32 + quad * 8;
        bfrag a = *(const bfrag*)&sbuf[wv * 16 + n15][kk];
#pragma unroll
        for (int c = 0; c < 8; ++c) {
            bfrag b = *(const bfrag*)&Wet[(c * 16 + n15) * 128 + kk];
            acc[c] = __builtin_amdgcn_mfma_f32_16x16x32_bf16(a, b, acc[c], 0, 0, 0);
        }
    }
    __builtin_amdgcn_s_setprio(0);
    // Overlay e (bf16) onto this wave's rows. C layout: col=c*16+n15, row=quad*4+r.
#pragma unroll
    for (int c = 0; c < 8; ++c)
#pragma unroll
        for (int r = 0; r < 4; ++r)
            sbuf[wv * 16 + quad * 4 + r][c * 16 + n15] = (short)f2bf(acc[c][r]);

    wave_lds_fence();   // overlay writes -> cross-lane e reads (within wave)

    // Phase 3: alpha + exp + fused segmented aggregation. Lane owns channels {2*lane, 2*lane+1}.
    int h = lane >> 5;
    float accx = 0.f, accy = 0.f, dacc = 0.f;
    int cur_d = s_dst[wv * 16];

    LOADQ(k2, q2, v2, 2);
    PROC(k0, q0, v0, 0);
    LOADQ(k3, q3, v3, 3);
    PROC(k1, q1, v1, 1);
    PROC(k2, q2, v2, 2);
    PROC(k3, q3, v3, 3);

    {   // final flush
        float* np = &num[(size_t)cur_d * CDIM + 2 * lane];
        unsafeAtomicAdd(np, accx);
        unsafeAtomicAdd(np + 1, accy);
        if ((lane & 31) == 0) unsafeAtomicAdd(&den[cur_d * 2 + h], dacc);
    }
}

// ---------------- normalize: out += num / (den + eps) ----------------
__global__ __launch_bounds__(256)
void norm_kernel(const float* __restrict__ num, const float* __restrict__ den,
                 float* __restrict__ out, int N) {
    int idx = blockIdx.x * 256 + threadIdx.x;   // one float4 per thread
    if (idx >= N * 32) return;
    int n = idx >> 5, c4 = idx & 31;
    int h = c4 >> 4;                            // 4-chunks never cross the head boundary
    float inv = 1.f / (den[n * 2 + h] + 1e-16f);
    float4 nm = ((const float4*)num)[idx];
    float4* op = (float4*)out + idx;
    float4 o = *op;
    o.x = fmaf(nm.x, inv, o.x);
    o.y = fmaf(nm.y, inv, o.y);
    o.z = fmaf(nm.z, inv, o.z);
    o.w = fmaf(nm.w, inv, o.w);
    *op = o;
}

extern "C" void kernel_launch(void* const* d_in, const int* in_sizes, int n_in,
                              void* d_out, int out_size, void* d_ws, size_t ws_size,
                              hipStream_t stream) {
    const float* x       = (const float*)d_in[0];
    const int*   last_up = (const int*)d_in[1];
    const int*   ei      = (const int*)d_in[2];
    const int*   tarr    = (const int*)d_in[3];
    const float* msg     = (const float*)d_in[4];
    const float* time_w  = (const float*)d_in[5];
    const float* time_b  = (const float*)d_in[6];
    const float* Wq = (const float*)d_in[7];  const float* bq = (const float*)d_in[8];
    const float* Wk = (const float*)d_in[9];  const float* bk = (const float*)d_in[10];
    const float* Wv = (const float*)d_in[11]; const float* bv = (const float*)d_in[12];
    const float* We = (const float*)d_in[13];
    const float* Wskip = (const float*)d_in[14]; const float* bskip = (const float*)d_in[15];
    float* out = (float*)d_out;

    int N = in_sizes[0] / CDIM;
    int E = in_sizes[3];
    int nb = (N + 1023) >> 10;

    char* ws = (char*)d_ws;
    size_t off = 0;
#define ALLOC(ptr, type, nelem) type* ptr = (type*)(ws + off); off = (off + (size_t)(nelem) * sizeof(type) + 255) & ~(size_t)255
    ALLOC(q_,    float, (size_t)N * CDIM);
    ALLOC(kbf_,  short, (size_t)N * CDIM);
    ALLOC(vbf_,  short, (size_t)N * CDIM);
    ALLOC(num,   float, (size_t)N * CDIM + 2 * N);   // den lives right after num (one memset)
    float* den_ = num + (size_t)N * CDIM;
    ALLOC(count, int,   N + 64);          // flag lives right after count (one memset)
    int* flag = count + N;
    ALLOC(cur,    int,  N);
    ALLOC(bsum,   int,  nb + 64);
    ALLOC(ed_s,   int4, (size_t)E + 64);  // 64-entry zeroed tail for guard-free reads
    ALLOC(Wt,     short, 4 * 16384);
    ALLOC(Wet,    short, 16384);
#undef ALLOC

    // zero count + flag, num + den, and the ed_s tail (ws is poisoned before each call)
    hipMemsetAsync(count, 0, (size_t)(N + 64) * 4, stream);
    hipMemsetAsync(num, 0, ((size_t)N * CDIM + 2 * N) * sizeof(float), stream);
    hipMemsetAsync(ed_s + E, 0, 64 * sizeof(int4), stream);

    int samp = E < 65536 ? E : 65536;
    detect_kernel<<<(samp + 255) / 256, 256, 0, stream>>>(ei, samp, flag);
    hist_kernel<<<(E + 255) / 256, 256, 0, stream>>>(ei, E, flag, count);
    scan1_kernel<<<nb, 1024, 0, stream>>>(count, N, cur, bsum);
    scan2_kernel<<<1, 64, 0, stream>>>(bsum, nb);
    scatter_kernel<<<(E + 255) / 256, 256, 0, stream>>>(ei, E, flag, tarr, last_up,
                                                        cur, bsum, ed_s);
    wconv_kernel<<<(5 * 16384 + 255) / 256, 256, 0, stream>>>(Wq, Wk, Wv, Wskip, We, Wt, Wet);
    proj_kernel<<<(N + 63) / 64, 256, 0, stream>>>(x, Wt, bq, bk, bv, bskip,
                                                   q_, kbf_, vbf_, out, N);
    edge_kernel<<<(E + 63) / 64, 256, 0, stream>>>(ed_s, msg, time_w, time_b, Wet,
                                                   q_, kbf_, vbf_, num, den_, E);
    norm_kernel<<<(N * 32 + 255) / 256, 256, 0, stream>>>(num, den_, out, N);
}

// Round 5
// 570.954 us; speedup vs baseline: 1.1767x; 1.1767x over previous
//
#include <hip/hip_runtime.h>
#include <hip/hip_bf16.h>

typedef __hip_bfloat16 bf16;
typedef __attribute__((ext_vector_type(8))) short bfrag;   // 8 bf16 = 4 VGPRs
typedef __attribute__((ext_vector_type(4))) float ffrag;   // 4 fp32 acc

#define CDIM 128
#define TDIMC 64
#define MSGD 64
#define INV2PI 0.15915494309189535f
#define WCONV_BLOCKS 320   // ceil(5*16384/256)

__device__ __forceinline__ unsigned short f2bf(float f) {
    union { __hip_bfloat16 h; unsigned short u; } cv;
    cv.h = __float2bfloat16(f);
    return cv.u;
}

// fast cos for pre-scaled (revolutions) argument: cos(2*pi*x)
__device__ __forceinline__ float fcos_rev(float xr) {
    float fr, c;
    asm("v_fract_f32 %0, %1" : "=v"(fr) : "v"(xr));   // [0,1) — v_cos takes revolutions
    asm("v_cos_f32 %0, %1" : "=v"(c) : "v"(fr));
    return c;
}

// ---------------- prep: wconv ∪ hist (independent roles, one launch) ----------------
// hist does per-wave inline dtype detect: sample ei[2e+1] (int64 high word) across the
// wave; any nonzero -> data is int32. P(false negative on random int32 ids) ~ (1/N)^64.
__global__ __launch_bounds__(256)
void prep_kernel(const int* __restrict__ ei, int E, int* __restrict__ count,
                 const float* __restrict__ Wq, const float* __restrict__ Wk,
                 const float* __restrict__ Wv, const float* __restrict__ Ws,
                 const float* __restrict__ We,
                 short* __restrict__ Wt, short* __restrict__ Wet) {
    int b = blockIdx.x;
    if (b < WCONV_BLOCKS) {     // ---- weight pre-transpose + bf16 convert ----
        int idx = b * 256 + threadIdx.x;
        if (idx >= 5 * 16384) return;
        int mat = idx >> 14;
        int r = idx & 16383;
        int n = r >> 7, kk = r & 127;
        const float* W = (mat == 0) ? Wq : (mat == 1) ? Wk : (mat == 2) ? Wv : (mat == 3) ? Ws : We;
        short bv = (short)f2bf(W[kk * 128 + n]);
        if (mat < 4) Wt[(size_t)mat * 16384 + n * 128 + kk] = bv;
        else         Wet[n * 128 + kk] = bv;
    } else {                    // ---- dst histogram ----
        int e = (b - WCONV_BLOCKS) * 256 + threadIdx.x;
        int probe = (e < E) ? ei[2 * e + 1] : 0;   // index <= 2E-1: safe in both dtypes
        int is32 = (__ballot(probe != 0) != 0ULL);
        if (e < E) {
            int d = is32 ? ei[E + e] : ei[2 * (E + e)];
            atomicAdd(&count[d], 1);
        }
    }
}

// ---------------- parallel scan: block-local pass ----------------
__global__ __launch_bounds__(1024)
void scan1_kernel(const int* __restrict__ count, int N,
                  int* __restrict__ cur, int* __restrict__ bsum) {
    __shared__ int wsum[16];
    __shared__ int woff[16];
    int t = threadIdx.x;
    int lane = t & 63, wv = t >> 6;
    int i = blockIdx.x * 1024 + t;
    int v = (i < N) ? count[i] : 0;
    int incl = v;
#pragma unroll
    for (int off = 1; off < 64; off <<= 1) {
        int n = __shfl_up(incl, off, 64);
        if (lane >= off) incl += n;
    }
    if (lane == 63) wsum[wv] = incl;
    __syncthreads();
    if (wv == 0) {
        int ws = (lane < 16) ? wsum[lane] : 0;
        int wi = ws;
#pragma unroll
        for (int off = 1; off < 16; off <<= 1) {
            int n = __shfl_up(wi, off, 64);
            if (lane >= off) wi += n;
        }
        if (lane < 16) woff[lane] = wi - ws;   // exclusive wave offset
        if (lane == 15) bsum[blockIdx.x] = wi; // block total
    }
    __syncthreads();
    if (i < N) cur[i] = woff[wv] + incl - v;
}

// ---------------- parallel scan: scan the block totals ----------------
__global__ void scan2_kernel(int* __restrict__ bsum, int nb) {
    int lane = threadIdx.x;   // launched with 64 threads
    int carry = 0;
    for (int base = 0; base < nb; base += 64) {
        int i = base + lane;
        int v = (i < nb) ? bsum[i] : 0;
        int incl = v;
#pragma unroll
        for (int off = 1; off < 64; off <<= 1) {
            int n = __shfl_up(incl, off, 64);
            if (lane >= off) incl += n;
        }
        if (i < nb) bsum[i] = carry + incl - v;   // exclusive
        carry += __shfl(incl, 63, 64);
    }
}

// ---------------- sp: proj ∪ scatter (independent roles, one launch) ----------------
// proj: MFMA node projections, wave w -> {q(f32), kv(bf16 interleaved), skip(f32)->out}
// scatter: dst-sorted packed int4 rows + rel_t precompute.
__global__ __launch_bounds__(256)
void sp_kernel(const float* __restrict__ x, const short* __restrict__ Wt,
               const float* __restrict__ bq, const float* __restrict__ bk,
               const float* __restrict__ bv, const float* __restrict__ bs,
               float* __restrict__ q, short* __restrict__ kvs,
               float* __restrict__ out, int N, int PB,
               const int* __restrict__ ei, int E,
               const int* __restrict__ tarr, const int* __restrict__ last_update,
               int* __restrict__ cur, const int* __restrict__ bsum,
               int4* __restrict__ ed_s) {
    __shared__ __attribute__((aligned(16))) short sx[64][136];
    int tid = threadIdx.x;
    if (blockIdx.x >= PB) {     // ---------------- scatter role ----------------
        int e = (blockIdx.x - PB) * 256 + tid;
        int probe = (e < E) ? ei[2 * e + 1] : 0;   // shares line with src low word
        int is32 = (__ballot(probe != 0) != 0ULL);
        if (e >= E) return;
        int s = is32 ? ei[e] : ei[2 * e];
        int d = is32 ? ei[E + e] : ei[2 * (E + e)];
        int pos = atomicAdd(&cur[d], 1) + bsum[d >> 10];
        float rt = (float)(last_update[s] - tarr[e]);
        ed_s[pos] = make_int4(s, d, e, __float_as_int(rt));
        return;
    }
    // ---------------- proj role ----------------
    int n0 = blockIdx.x * 64;
    const float4* x4 = (const float4*)x;
    for (int i = tid; i < 64 * 32; i += 256) {
        int nl = i >> 5, c4 = i & 31;
        int n = n0 + nl;
        float4 f = (n < N) ? x4[(size_t)n * 32 + c4] : make_float4(0.f, 0.f, 0.f, 0.f);
        unsigned int lo = ((unsigned int)f2bf(f.y) << 16) | f2bf(f.x);
        unsigned int hi = ((unsigned int)f2bf(f.w) << 16) | f2bf(f.z);
        *(uint2*)&sx[nl][c4 * 4] = make_uint2(lo, hi);
    }
    __syncthreads();

    int lane = tid & 63, wv = tid >> 6;
    int n15 = lane & 15, quad = lane >> 4;
    const short* W = Wt + (size_t)wv * 16384;
    const float* bias = (wv == 0) ? bq : (wv == 1) ? bk : (wv == 2) ? bv : bs;

    ffrag acc[4][8];
#pragma unroll
    for (int r = 0; r < 4; ++r)
#pragma unroll
        for (int c = 0; c < 8; ++c)
            acc[r][c] = (ffrag){0.f, 0.f, 0.f, 0.f};

#pragma unroll
    for (int kc = 0; kc < 4; ++kc) {
        int kk = kc * 32 + quad * 8;
        bfrag a[4];
#pragma unroll
        for (int r = 0; r < 4; ++r)
            a[r] = *(const bfrag*)&sx[r * 16 + n15][kk];
#pragma unroll
        for (int c = 0; c < 8; ++c) {
            bfrag b = *(const bfrag*)&W[(c * 16 + n15) * 128 + kk];
#pragma unroll
            for (int r = 0; r < 4; ++r)
                acc[r][c] = __builtin_amdgcn_mfma_f32_16x16x32_bf16(a[r], b, acc[r][c], 0, 0, 0);
        }
    }

    if (wv == 1 || wv == 2) {          // k, v -> interleaved bf16 kv-pack
        int isv = (wv == 2) ? 2 : 0;   // shorts [l*4+0,1]=k pair, [l*4+2,3]=v pair
#pragma unroll
        for (int c = 0; c < 8; ++c) {
            int col = c * 16 + n15;
            float bval = bias[col];
            int coff = (col >> 1) * 4 + (col & 1) + isv;
#pragma unroll
            for (int r = 0; r < 4; ++r) {
#pragma unroll
                for (int g = 0; g < 4; ++g) {
                    int n = n0 + r * 16 + quad * 4 + g;
                    if (n < N) kvs[(size_t)n * 256 + coff] = (short)f2bf(acc[r][c][g] + bval);
                }
            }
        }
    } else {                           // q, skip -> f32
        float* dstp = (wv == 0) ? q : out;
#pragma unroll
        for (int c = 0; c < 8; ++c) {
            int col = c * 16 + n15;
            float bval = bias[col];
#pragma unroll
            for (int r = 0; r < 4; ++r) {
#pragma unroll
                for (int g = 0; g < 4; ++g) {
                    int n = n0 + r * 16 + quad * 4 + g;
                    if (n < N) dstp[(size_t)n * CDIM + col] = acc[r][c][g] + bval;
                }
            }
        }
    }
}

// ---------------- MFMA edge kernel (round-3 structure), fused seg-softmax agg ----------
// Block = 64 dst-sorted edges, 4 waves x 16 edges. sbuf: edge_attr staged, e overlaid.
// Overlay WRITE needs no barrier (depends on all A-frag ds_reads via the MFMA chain);
// the phase-3 READ of e needs a barrier: raw s_barrier + lgkmcnt(0) (no vmcnt drain,
// so prefetched batch-0/1 gathers stay in flight across it); sched_barrier(0) per #18.
// ed_s reads clamp to E-1: tail rows duplicate the last edge and are masked by exv=0.
#define LOADQ(KVA, QA, JB) do {                                                 \
    _Pragma("unroll")                                                           \
    for (int u = 0; u < 4; ++u) {                                               \
        int el = wv * 16 + (JB) * 4 + u;                                        \
        int s = s_src[el], d = s_dst[el];                                       \
        KVA[u] = kv[(size_t)s * 64 + lane];                                     \
        QA[u] = *(const float2*)&q[(size_t)d * CDIM + 2 * lane];                \
    } } while (0)

#define PROC(KVA, QA, JB) do {                                                  \
    _Pragma("unroll")                                                           \
    for (int u = 0; u < 4; ++u) {                                               \
        int el = wv * 16 + (JB) * 4 + u;                                        \
        unsigned int ep = *(const unsigned int*)&sbuf[el][2 * lane];            \
        float ex0 = __uint_as_float(ep << 16);                                  \
        float ex1 = __uint_as_float(ep & 0xffff0000u);                          \
        float kx = __uint_as_float(KVA[u].x << 16) + ex0;                       \
        float ky = __uint_as_float(KVA[u].x & 0xffff0000u) + ex1;               \
        float p = QA[u].x * kx + QA[u].y * ky;                                  \
        _Pragma("unroll")                                                       \
        for (int off = 1; off < 32; off <<= 1) p += __shfl_xor(p, off, 32);     \
        float exv = (e0 + el < E) ? __expf(p * 0.125f) : 0.f;                   \
        int d = s_dst[el];                                                      \
        if (d != cur_d) {   /* uniform across wave */                           \
            float* np = &num[(size_t)cur_d * CDIM + 2 * lane];                  \
            unsafeAtomicAdd(np, accx);                                          \
            unsafeAtomicAdd(np + 1, accy);                                      \
            if ((lane & 31) == 0) unsafeAtomicAdd(&den[cur_d * 2 + h], dacc);   \
            accx = 0.f; accy = 0.f; dacc = 0.f;                                 \
            cur_d = d;                                                          \
        }                                                                       \
        float vx = __uint_as_float(KVA[u].y << 16) + ex0;                       \
        float vy = __uint_as_float(KVA[u].y & 0xffff0000u) + ex1;               \
        accx = fmaf(vx, exv, accx);                                             \
        accy = fmaf(vy, exv, accy);                                             \
        dacc += exv;                                                            \
    } } while (0)

__global__ __launch_bounds__(256)
void edge_kernel(const int4* __restrict__ ed_s,
                 const float* __restrict__ msg,
                 const float* __restrict__ time_w, const float* __restrict__ time_b,
                 const short* __restrict__ Wet,
                 const float* __restrict__ q, const uint2* __restrict__ kv,
                 float* __restrict__ num, float* __restrict__ den,
                 int E) {
    __shared__ __attribute__((aligned(16))) short sbuf[64][136];
    __shared__ int s_src[64], s_dst[64];
    int tid = threadIdx.x;
    int Em1 = E - 1;

    // Bijective XCD-aware swizzle: each XCD owns a contiguous chunk of dst-sorted edges.
    int nwg = gridDim.x;
    int q8 = nwg >> 3, r8 = nwg & 7;
    int xcd = blockIdx.x & 7, idx8 = blockIdx.x >> 3;
    int bid = (xcd < r8 ? xcd * (q8 + 1) : r8 * (q8 + 1) + (xcd - r8) * q8) + idx8;
    int e0 = bid * 64;

    // Phase A: stage edge meta + edge_attr (clamped reads, no tail memset needed).
    if (tid < 64) {
        int4 ed = ed_s[min(e0 + tid, Em1)];
        s_src[tid] = ed.x;
        s_dst[tid] = ed.y;
    }
    {   // cos half: fast revolutions-space cos
#pragma unroll
        for (int ii = 0; ii < 8; ++ii) {
            int i = tid + ii * 256;
            int el = i >> 5, c2 = i & 31;
            float rt = __int_as_float(ed_s[min(e0 + el, Em1)].w);
            float2 w = ((const float2*)time_w)[c2];
            float2 b = ((const float2*)time_b)[c2];
            float c0 = fcos_rev(fmaf(rt, w.x * INV2PI, b.x * INV2PI));
            float c1 = fcos_rev(fmaf(rt, w.y * INV2PI, b.y * INV2PI));
            unsigned int pk = ((unsigned int)f2bf(c1) << 16) | f2bf(c0);
            *(unsigned int*)&sbuf[el][c2 * 2] = pk;
        }
        const float4* msg4 = (const float4*)msg;
#pragma unroll
        for (int jj = 0; jj < 4; ++jj) {
            int j = tid + jj * 256;
            int el = j >> 4, f4 = j & 15;
            int p = ed_s[min(e0 + el, Em1)].z;
            float4 m = msg4[(size_t)p * 16 + f4];
            unsigned int lo = ((unsigned int)f2bf(m.y) << 16) | f2bf(m.x);
            unsigned int hi = ((unsigned int)f2bf(m.w) << 16) | f2bf(m.z);
            *(uint2*)&sbuf[el][TDIMC + f4 * 4] = make_uint2(lo, hi);
        }
    }
    __syncthreads();

    int lane = tid & 63;
    int wv = tid >> 6;            // wave -> edges wv*16 .. wv*16+15
    int n15 = lane & 15, quad = lane >> 4;

    // Prefetch phase-3 batches 0,1 — latency hides under the MFMA phase AND survives
    // the overlay barrier (no vmcnt drain there).
    uint2 kv0[4], kv1[4], kv2[4], kv3[4];
    float2 q0[4], q1[4], q2[4], q3[4];
    LOADQ(kv0, q0, 0);
    LOADQ(kv1, q1, 1);

    ffrag acc[8];
#pragma unroll
    for (int c = 0; c < 8; ++c) acc[c] = (ffrag){0.f, 0.f, 0.f, 0.f};
#pragma unroll
    for (int kc = 0; kc < 4; ++kc) {
        int kk = kc * 32 + quad * 8;
        bfrag a = *(const bfrag*)&sbuf[wv * 16 + n15][kk];
#pragma unroll
        for (int c = 0; c < 8; ++c) {
            bfrag b = *(const bfrag*)&Wet[(c * 16 + n15) * 128 + kk];
            acc[c] = __builtin_amdgcn_mfma_f32_16x16x32_bf16(a, b, acc[c], 0, 0, 0);
        }
    }
    // Overlay e (bf16) onto this wave's rows. C layout: col=c*16+n15, row=quad*4+r.
#pragma unroll
    for (int c = 0; c < 8; ++c)
#pragma unroll
        for (int r = 0; r < 4; ++r)
            sbuf[wv * 16 + quad * 4 + r][c * 16 + n15] = (short)f2bf(acc[c][r]);

    // Barrier WITHOUT vmcnt drain: order LDS overlay writes (lgkmcnt) then s_barrier.
    asm volatile("s_waitcnt lgkmcnt(0)" ::: "memory");
    __builtin_amdgcn_s_barrier();
    __builtin_amdgcn_sched_barrier(0);

    // Phase 3: alpha + exp + fused segmented aggregation. Lane owns channels {2*lane, 2*lane+1}.
    int h = lane >> 5;
    float accx = 0.f, accy = 0.f, dacc = 0.f;
    int cur_d = s_dst[wv * 16];

    LOADQ(kv2, q2, 2);
    PROC(kv0, q0, 0);
    LOADQ(kv3, q3, 3);
    PROC(kv1, q1, 1);
    PROC(kv2, q2, 2);
    PROC(kv3, q3, 3);

    {   // final flush
        float* np = &num[(size_t)cur_d * CDIM + 2 * lane];
        unsafeAtomicAdd(np, accx);
        unsafeAtomicAdd(np + 1, accy);
        if ((lane & 31) == 0) unsafeAtomicAdd(&den[cur_d * 2 + h], dacc);
    }
}

// ---------------- normalize: out += num / (den + eps) ----------------
__global__ __launch_bounds__(256)
void norm_kernel(const float* __restrict__ num, const float* __restrict__ den,
                 float* __restrict__ out, int N) {
    int idx = blockIdx.x * 256 + threadIdx.x;   // one float4 per thread
    if (idx >= N * 32) return;
    int n = idx >> 5, c4 = idx & 31;
    int h = c4 >> 4;                            // 4-chunks never cross the head boundary
    float inv = 1.f / (den[n * 2 + h] + 1e-16f);
    float4 nm = ((const float4*)num)[idx];
    float4* op = (float4*)out + idx;
    float4 o = *op;
    o.x = fmaf(nm.x, inv, o.x);
    o.y = fmaf(nm.y, inv, o.y);
    o.z = fmaf(nm.z, inv, o.z);
    o.w = fmaf(nm.w, inv, o.w);
    *op = o;
}

extern "C" void kernel_launch(void* const* d_in, const int* in_sizes, int n_in,
                              void* d_out, int out_size, void* d_ws, size_t ws_size,
                              hipStream_t stream) {
    const float* x       = (const float*)d_in[0];
    const int*   last_up = (const int*)d_in[1];
    const int*   ei      = (const int*)d_in[2];
    const int*   tarr    = (const int*)d_in[3];
    const float* msg     = (const float*)d_in[4];
    const float* time_w  = (const float*)d_in[5];
    const float* time_b  = (const float*)d_in[6];
    const float* Wq = (const float*)d_in[7];  const float* bq = (const float*)d_in[8];
    const float* Wk = (const float*)d_in[9];  const float* bk = (const float*)d_in[10];
    const float* Wv = (const float*)d_in[11]; const float* bv = (const float*)d_in[12];
    const float* We = (const float*)d_in[13];
    const float* Wskip = (const float*)d_in[14]; const float* bskip = (const float*)d_in[15];
    float* out = (float*)d_out;

    int N = in_sizes[0] / CDIM;
    int E = in_sizes[3];
    int nb = (N + 1023) >> 10;

    char* ws = (char*)d_ws;
    size_t off = 0;
#define ALLOC(ptr, type, nelem) type* ptr = (type*)(ws + off); off = (off + (size_t)(nelem) * sizeof(type) + 255) & ~(size_t)255
    ALLOC(q_,    float, (size_t)N * CDIM);
    ALLOC(kvs_,  short, (size_t)N * 256);            // interleaved bf16 k|v pairs
    ALLOC(num,   float, (size_t)N * CDIM + 2 * N + N);  // num | den | count -> ONE memset
    float* den_ = num + (size_t)N * CDIM;
    int* count  = (int*)(den_ + 2 * N);
    ALLOC(cur,    int,  N);
    ALLOC(bsum,   int,  nb + 64);
    ALLOC(ed_s,   int4, (size_t)E);
    ALLOC(Wt,     short, 4 * 16384);
    ALLOC(Wet,    short, 16384);
#undef ALLOC

    // single zero region: num | den | count (ws is poisoned before each timed call)
    hipMemsetAsync(num, 0, ((size_t)N * CDIM + 3 * N) * sizeof(float), stream);

    int histB = (E + 255) / 256;
    int PB = (N + 63) / 64;
    prep_kernel<<<WCONV_BLOCKS + histB, 256, 0, stream>>>(ei, E, count,
                                                          Wq, Wk, Wv, Wskip, We, Wt, Wet);
    scan1_kernel<<<nb, 1024, 0, stream>>>(count, N, cur, bsum);
    scan2_kernel<<<1, 64, 0, stream>>>(bsum, nb);
    sp_kernel<<<PB + histB, 256, 0, stream>>>(x, Wt, bq, bk, bv, bskip,
                                              q_, kvs_, out, N, PB,
                                              ei, E, tarr, last_up, cur, bsum, ed_s);
    edge_kernel<<<(E + 63) / 64, 256, 0, stream>>>(ed_s, msg, time_w, time_b, Wet,
                                                   q_, (const uint2*)kvs_, num, den_, E);
    norm_kernel<<<(N * 32 + 255) / 256, 256, 0, stream>>>(num, den_, out, N);
}

// Round 6
// 559.657 us; speedup vs baseline: 1.2005x; 1.0202x over previous
//
#include <hip/hip_runtime.h>
#include <hip/hip_bf16.h>

typedef __hip_bfloat16 bf16;
typedef __attribute__((ext_vector_type(8))) short bfrag;   // 8 bf16 = 4 VGPRs
typedef __attribute__((ext_vector_type(4))) float ffrag;   // 4 fp32 acc

#define CDIM 128
#define TDIMC 64
#define MSGD 64
#define INV2PI 0.15915494309189535f
#define WCONV_BLOCKS 320   // ceil(5*16384/256)

__device__ __forceinline__ unsigned short f2bf(float f) {
    union { __hip_bfloat16 h; unsigned short u; } cv;
    cv.h = __float2bfloat16(f);
    return cv.u;
}

// fast cos for pre-scaled (revolutions) argument: cos(2*pi*x)
__device__ __forceinline__ float fcos_rev(float xr) {
    float fr, c;
    asm("v_fract_f32 %0, %1" : "=v"(fr) : "v"(xr));   // [0,1) — v_cos takes revolutions
    asm("v_cos_f32 %0, %1" : "=v"(c) : "v"(fr));
    return c;
}

// ---------------- prep: wconv ∪ hist (independent roles, one launch) ----------------
__global__ __launch_bounds__(256)
void prep_kernel(const int* __restrict__ ei, int E, int* __restrict__ count,
                 const float* __restrict__ Wq, const float* __restrict__ Wk,
                 const float* __restrict__ Wv, const float* __restrict__ Ws,
                 const float* __restrict__ We,
                 short* __restrict__ Wt, short* __restrict__ Wet) {
    int b = blockIdx.x;
    if (b < WCONV_BLOCKS) {     // ---- weight pre-transpose + bf16 convert ----
        int idx = b * 256 + threadIdx.x;
        if (idx >= 5 * 16384) return;
        int mat = idx >> 14;
        int r = idx & 16383;
        int n = r >> 7, kk = r & 127;
        const float* W = (mat == 0) ? Wq : (mat == 1) ? Wk : (mat == 2) ? Wv : (mat == 3) ? Ws : We;
        short bv = (short)f2bf(W[kk * 128 + n]);
        if (mat < 4) Wt[(size_t)mat * 16384 + n * 128 + kk] = bv;
        else         Wet[n * 128 + kk] = bv;
    } else {                    // ---- dst histogram with inline per-wave dtype detect ----
        int e = (b - WCONV_BLOCKS) * 256 + threadIdx.x;
        int probe = (e < E) ? ei[2 * e + 1] : 0;   // index <= 2E-1: safe in both dtypes
        int is32 = (__ballot(probe != 0) != 0ULL);
        if (e < E) {
            int d = is32 ? ei[E + e] : ei[2 * (E + e)];
            atomicAdd(&count[d], 1);
        }
    }
}

// ---------------- parallel scan: block-local pass ----------------
__global__ __launch_bounds__(1024)
void scan1_kernel(const int* __restrict__ count, int N,
                  int* __restrict__ cur, int* __restrict__ bsum) {
    __shared__ int wsum[16];
    __shared__ int woff[16];
    int t = threadIdx.x;
    int lane = t & 63, wv = t >> 6;
    int i = blockIdx.x * 1024 + t;
    int v = (i < N) ? count[i] : 0;
    int incl = v;
#pragma unroll
    for (int off = 1; off < 64; off <<= 1) {
        int n = __shfl_up(incl, off, 64);
        if (lane >= off) incl += n;
    }
    if (lane == 63) wsum[wv] = incl;
    __syncthreads();
    if (wv == 0) {
        int ws = (lane < 16) ? wsum[lane] : 0;
        int wi = ws;
#pragma unroll
        for (int off = 1; off < 16; off <<= 1) {
            int n = __shfl_up(wi, off, 64);
            if (lane >= off) wi += n;
        }
        if (lane < 16) woff[lane] = wi - ws;   // exclusive wave offset
        if (lane == 15) bsum[blockIdx.x] = wi; // block total
    }
    __syncthreads();
    if (i < N) cur[i] = woff[wv] + incl - v;
}

// ---------------- parallel scan: scan the block totals ----------------
__global__ void scan2_kernel(int* __restrict__ bsum, int nb) {
    int lane = threadIdx.x;   // launched with 64 threads
    int carry = 0;
    for (int base = 0; base < nb; base += 64) {
        int i = base + lane;
        int v = (i < nb) ? bsum[i] : 0;
        int incl = v;
#pragma unroll
        for (int off = 1; off < 64; off <<= 1) {
            int n = __shfl_up(incl, off, 64);
            if (lane >= off) incl += n;
        }
        if (i < nb) bsum[i] = carry + incl - v;   // exclusive
        carry += __shfl(incl, 63, 64);
    }
}

// ---------------- sp: proj ∪ scatter (independent roles, one launch) ----------------
// proj uses SWAPPED mfma operands -> acc holds Cᵀ: a lane's 4 acc elems = 4 consecutive
// output CHANNELS of one node -> coalesced float4 (q/skip) and dword-pair (kv) stores.
// 128 scattered scalar stores/thread -> 32 float4 or 64 dword stores/thread.
__global__ __launch_bounds__(256)
void sp_kernel(const float* __restrict__ x, const short* __restrict__ Wt,
               const float* __restrict__ bq, const float* __restrict__ bk,
               const float* __restrict__ bv, const float* __restrict__ bs,
               float* __restrict__ q, unsigned int* __restrict__ kvu,
               float* __restrict__ out, int N, int PB,
               const int* __restrict__ ei, int E,
               const int* __restrict__ tarr, const int* __restrict__ last_update,
               int* __restrict__ cur, const int* __restrict__ bsum,
               int4* __restrict__ ed_s) {
    __shared__ __attribute__((aligned(16))) short sx[64][136];
    int tid = threadIdx.x;
    if (blockIdx.x >= PB) {     // ---------------- scatter role ----------------
        int e = (blockIdx.x - PB) * 256 + tid;
        int probe = (e < E) ? ei[2 * e + 1] : 0;
        int is32 = (__ballot(probe != 0) != 0ULL);
        if (e >= E) return;
        int s = is32 ? ei[e] : ei[2 * e];
        int d = is32 ? ei[E + e] : ei[2 * (E + e)];
        int pos = atomicAdd(&cur[d], 1) + bsum[d >> 10];
        float rt = (float)(last_update[s] - tarr[e]);
        ed_s[pos] = make_int4(s, d, e, __float_as_int(rt));
        return;
    }
    // ---------------- proj role ----------------
    int n0 = blockIdx.x * 64;
    const float4* x4 = (const float4*)x;
    for (int i = tid; i < 64 * 32; i += 256) {
        int nl = i >> 5, c4 = i & 31;
        int n = n0 + nl;
        float4 f = (n < N) ? x4[(size_t)n * 32 + c4] : make_float4(0.f, 0.f, 0.f, 0.f);
        unsigned int lo = ((unsigned int)f2bf(f.y) << 16) | f2bf(f.x);
        unsigned int hi = ((unsigned int)f2bf(f.w) << 16) | f2bf(f.z);
        *(uint2*)&sx[nl][c4 * 4] = make_uint2(lo, hi);
    }
    __syncthreads();

    int lane = tid & 63, wv = tid >> 6;
    int n15 = lane & 15, quad = lane >> 4;
    const short* W = Wt + (size_t)wv * 16384;
    const float* bias = (wv == 0) ? bq : (wv == 1) ? bk : (wv == 2) ? bv : bs;

    ffrag acc[8][4];   // [oc_tile][node_tile] — transposed output
#pragma unroll
    for (int oc = 0; oc < 8; ++oc)
#pragma unroll
        for (int nt = 0; nt < 4; ++nt)
            acc[oc][nt] = (ffrag){0.f, 0.f, 0.f, 0.f};

#pragma unroll
    for (int kc = 0; kc < 4; ++kc) {
        int kk = kc * 32 + quad * 8;
        bfrag b[4];
#pragma unroll
        for (int nt = 0; nt < 4; ++nt)
            b[nt] = *(const bfrag*)&sx[nt * 16 + n15][kk];
#pragma unroll
        for (int oc = 0; oc < 8; ++oc) {
            bfrag a = *(const bfrag*)&W[(oc * 16 + n15) * 128 + kk];
#pragma unroll
            for (int nt = 0; nt < 4; ++nt)
                acc[oc][nt] = __builtin_amdgcn_mfma_f32_16x16x32_bf16(a, b[nt], acc[oc][nt], 0, 0, 0);
        }
    }

    // Cᵀ layout: lane holds node = nt*16+n15, channels oc*16+quad*4 .. +3 (consecutive!)
    if (wv == 1 || wv == 2) {          // k, v -> interleaved bf16 kv-pack (dword pairs)
        int iv = wv - 1;               // dword idx = 2m+iv for col pair m
#pragma unroll
        for (int oc = 0; oc < 8; ++oc) {
            float4 b4 = *(const float4*)&bias[oc * 16 + quad * 4];
            int d0 = oc * 16 + quad * 4 + iv;
#pragma unroll
            for (int nt = 0; nt < 4; ++nt) {
                int n = n0 + nt * 16 + n15;
                if (n < N) {
                    ffrag a4 = acc[oc][nt];
                    unsigned int p0 = ((unsigned int)f2bf(a4[1] + b4.y) << 16) | f2bf(a4[0] + b4.x);
                    unsigned int p1 = ((unsigned int)f2bf(a4[3] + b4.w) << 16) | f2bf(a4[2] + b4.z);
                    kvu[(size_t)n * 128 + d0]     = p0;
                    kvu[(size_t)n * 128 + d0 + 2] = p1;
                }
            }
        }
    } else {                           // q, skip -> f32 coalesced float4
        float* dstp = (wv == 0) ? q : out;
#pragma unroll
        for (int oc = 0; oc < 8; ++oc) {
            float4 b4 = *(const float4*)&bias[oc * 16 + quad * 4];
#pragma unroll
            for (int nt = 0; nt < 4; ++nt) {
                int n = n0 + nt * 16 + n15;
                if (n < N) {
                    ffrag a4 = acc[oc][nt];
                    float4 o = make_float4(a4[0] + b4.x, a4[1] + b4.y, a4[2] + b4.z, a4[3] + b4.w);
                    *(float4*)&dstp[(size_t)n * CDIM + oc * 16 + quad * 4] = o;
                }
            }
        }
    }
}

// ---------------- MFMA edge kernel, fused seg-softmax agg ----------------
// Block = 64 dst-sorted edges, 4 waves x 16 edges. sbuf: edge_attr staged, e overlaid.
// SWAPPED mfma: acc = eᵀ -> lane's 4 acc elems = 4 consecutive channels of edge n15
// -> overlay is 8 ds_write_b64 (vs 32 ds_write_b16). Phase-3 read layout unchanged.
// ALL 4 phase-3 batches prefetch before MFMA; barrier is s_barrier + lgkmcnt(0) only
// (no vmcnt drain -> 32 gathers stay in flight across it); sched_barrier(0) per #18.
// ed_s reads clamp to E-1: tail rows duplicate the last edge, masked by exv=0.
#define LOADQ(KVA, QA, JB) do {                                                 \
    _Pragma("unroll")                                                           \
    for (int u = 0; u < 4; ++u) {                                               \
        int el = wv * 16 + (JB) * 4 + u;                                        \
        int s = s_src[el], d = s_dst[el];                                       \
        KVA[u] = kv[(size_t)s * 64 + lane];                                     \
        QA[u] = *(const float2*)&q[(size_t)d * CDIM + 2 * lane];                \
    } } while (0)

#define PROC(KVA, QA, JB) do {                                                  \
    _Pragma("unroll")                                                           \
    for (int u = 0; u < 4; ++u) {                                               \
        int el = wv * 16 + (JB) * 4 + u;                                        \
        unsigned int ep = *(const unsigned int*)&sbuf[el][2 * lane];            \
        float ex0 = __uint_as_float(ep << 16);                                  \
        float ex1 = __uint_as_float(ep & 0xffff0000u);                          \
        float kx = __uint_as_float(KVA[u].x << 16) + ex0;                       \
        float ky = __uint_as_float(KVA[u].x & 0xffff0000u) + ex1;               \
        float p = QA[u].x * kx + QA[u].y * ky;                                  \
        _Pragma("unroll")                                                       \
        for (int off = 1; off < 32; off <<= 1) p += __shfl_xor(p, off, 32);     \
        float exv = (e0 + el < E) ? __expf(p * 0.125f) : 0.f;                   \
        int d = s_dst[el];                                                      \
        if (d != cur_d) {   /* uniform across wave */                           \
            float* np = &num[(size_t)cur_d * CDIM + 2 * lane];                  \
            unsafeAtomicAdd(np, accx);                                          \
            unsafeAtomicAdd(np + 1, accy);                                      \
            if ((lane & 31) == 0) unsafeAtomicAdd(&den[cur_d * 2 + h], dacc);   \
            accx = 0.f; accy = 0.f; dacc = 0.f;                                 \
            cur_d = d;                                                          \
        }                                                                       \
        float vx = __uint_as_float(KVA[u].y << 16) + ex0;                       \
        float vy = __uint_as_float(KVA[u].y & 0xffff0000u) + ex1;               \
        accx = fmaf(vx, exv, accx);                                             \
        accy = fmaf(vy, exv, accy);                                             \
        dacc += exv;                                                            \
    } } while (0)

__global__ __launch_bounds__(256)
void edge_kernel(const int4* __restrict__ ed_s,
                 const float* __restrict__ msg,
                 const float* __restrict__ time_w, const float* __restrict__ time_b,
                 const short* __restrict__ Wet,
                 const float* __restrict__ q, const uint2* __restrict__ kv,
                 float* __restrict__ num, float* __restrict__ den,
                 int E) {
    __shared__ __attribute__((aligned(16))) short sbuf[64][136];
    __shared__ int s_src[64], s_dst[64];
    int tid = threadIdx.x;
    int Em1 = E - 1;

    // Bijective XCD-aware swizzle: each XCD owns a contiguous chunk of dst-sorted edges.
    int nwg = gridDim.x;
    int q8 = nwg >> 3, r8 = nwg & 7;
    int xcd = blockIdx.x & 7, idx8 = blockIdx.x >> 3;
    int bid = (xcd < r8 ? xcd * (q8 + 1) : r8 * (q8 + 1) + (xcd - r8) * q8) + idx8;
    int e0 = bid * 64;

    // Phase A: staging, 4 threads per edge, ONE ed_s read per thread.
    {
        int el = tid >> 2, sub = tid & 3;
        int4 ed = ed_s[min(e0 + el, Em1)];
        if (sub == 0) { s_src[el] = ed.x; s_dst[el] = ed.y; }
        float rt = __int_as_float(ed.w);
        // cos half: 8 pair-slots per thread
#pragma unroll
        for (int ii = 0; ii < 8; ++ii) {
            int c2 = sub * 8 + ii;
            float2 w = ((const float2*)time_w)[c2];
            float2 b = ((const float2*)time_b)[c2];
            float c0 = fcos_rev(fmaf(rt, w.x * INV2PI, b.x * INV2PI));
            float c1 = fcos_rev(fmaf(rt, w.y * INV2PI, b.y * INV2PI));
            unsigned int pk = ((unsigned int)f2bf(c1) << 16) | f2bf(c0);
            *(unsigned int*)&sbuf[el][c2 * 2] = pk;
        }
        // msg half: 4 float4 per thread (consecutive 64B chunk per thread)
        const float4* mrow = (const float4*)msg + (size_t)ed.z * 16;
#pragma unroll
        for (int jj = 0; jj < 4; ++jj) {
            int f4 = sub * 4 + jj;
            float4 m = mrow[f4];
            unsigned int lo = ((unsigned int)f2bf(m.y) << 16) | f2bf(m.x);
            unsigned int hi = ((unsigned int)f2bf(m.w) << 16) | f2bf(m.z);
            *(uint2*)&sbuf[el][TDIMC + f4 * 4] = make_uint2(lo, hi);
        }
    }
    __syncthreads();

    int lane = tid & 63;
    int wv = tid >> 6;            // wave -> edges wv*16 .. wv*16+15
    int n15 = lane & 15, quad = lane >> 4;

    // Prefetch ALL 4 phase-3 batches: 32 loads in flight, hidden under MFMA phase
    // and surviving the overlay barrier (no vmcnt drain there).
    uint2 kv0[4], kv1[4], kv2[4], kv3[4];
    float2 q0[4], q1[4], q2[4], q3[4];
    LOADQ(kv0, q0, 0);
    LOADQ(kv1, q1, 1);
    LOADQ(kv2, q2, 2);
    LOADQ(kv3, q3, 3);

    // SWAPPED-operand MFMA: acc[oc] = eᵀ tile [outch 16][edge 16]
    ffrag acc[8];
#pragma unroll
    for (int oc = 0; oc < 8; ++oc) acc[oc] = (ffrag){0.f, 0.f, 0.f, 0.f};
#pragma unroll
    for (int kc = 0; kc < 4; ++kc) {
        int kk = kc * 32 + quad * 8;
        bfrag b = *(const bfrag*)&sbuf[wv * 16 + n15][kk];
#pragma unroll
        for (int oc = 0; oc < 8; ++oc) {
            bfrag a = *(const bfrag*)&Wet[(oc * 16 + n15) * 128 + kk];
            acc[oc] = __builtin_amdgcn_mfma_f32_16x16x32_bf16(a, b, acc[oc], 0, 0, 0);
        }
    }
    // Overlay eᵀ: lane's edge = wv*16+n15, channels oc*16+quad*4..+3 -> one b64 write.
#pragma unroll
    for (int oc = 0; oc < 8; ++oc) {
        unsigned int lo = ((unsigned int)f2bf(acc[oc][1]) << 16) | f2bf(acc[oc][0]);
        unsigned int hi = ((unsigned int)f2bf(acc[oc][3]) << 16) | f2bf(acc[oc][2]);
        *(uint2*)&sbuf[wv * 16 + n15][oc * 16 + quad * 4] = make_uint2(lo, hi);
    }

    // Barrier WITHOUT vmcnt drain: order LDS overlay writes (lgkmcnt) then s_barrier.
    asm volatile("s_waitcnt lgkmcnt(0)" ::: "memory");
    __builtin_amdgcn_s_barrier();
    __builtin_amdgcn_sched_barrier(0);

    // Phase 3: alpha + exp + fused segmented aggregation. Lane owns channels {2*lane, 2*lane+1}.
    int h = lane >> 5;
    float accx = 0.f, accy = 0.f, dacc = 0.f;
    int cur_d = s_dst[wv * 16];

    PROC(kv0, q0, 0);
    PROC(kv1, q1, 1);
    PROC(kv2, q2, 2);
    PROC(kv3, q3, 3);

    {   // final flush
        float* np = &num[(size_t)cur_d * CDIM + 2 * lane];
        unsafeAtomicAdd(np, accx);
        unsafeAtomicAdd(np + 1, accy);
        if ((lane & 31) == 0) unsafeAtomicAdd(&den[cur_d * 2 + h], dacc);
    }
}

// ---------------- normalize: out += num / (den + eps) ----------------
__global__ __launch_bounds__(256)
void norm_kernel(const float* __restrict__ num, const float* __restrict__ den,
                 float* __restrict__ out, int N) {
    int idx = blockIdx.x * 256 + threadIdx.x;   // one float4 per thread
    if (idx >= N * 32) return;
    int n = idx >> 5, c4 = idx & 31;
    int h = c4 >> 4;                            // 4-chunks never cross the head boundary
    float inv = 1.f / (den[n * 2 + h] + 1e-16f);
    float4 nm = ((const float4*)num)[idx];
    float4* op = (float4*)out + idx;
    float4 o = *op;
    o.x = fmaf(nm.x, inv, o.x);
    o.y = fmaf(nm.y, inv, o.y);
    o.z = fmaf(nm.z, inv, o.z);
    o.w = fmaf(nm.w, inv, o.w);
    *op = o;
}

extern "C" void kernel_launch(void* const* d_in, const int* in_sizes, int n_in,
                              void* d_out, int out_size, void* d_ws, size_t ws_size,
                              hipStream_t stream) {
    const float* x       = (const float*)d_in[0];
    const int*   last_up = (const int*)d_in[1];
    const int*   ei      = (const int*)d_in[2];
    const int*   tarr    = (const int*)d_in[3];
    const float* msg     = (const float*)d_in[4];
    const float* time_w  = (const float*)d_in[5];
    const float* time_b  = (const float*)d_in[6];
    const float* Wq = (const float*)d_in[7];  const float* bq = (const float*)d_in[8];
    const float* Wk = (const float*)d_in[9];  const float* bk = (const float*)d_in[10];
    const float* Wv = (const float*)d_in[11]; const float* bv = (const float*)d_in[12];
    const float* We = (const float*)d_in[13];
    const float* Wskip = (const float*)d_in[14]; const float* bskip = (const float*)d_in[15];
    float* out = (float*)d_out;

    int N = in_sizes[0] / CDIM;
    int E = in_sizes[3];
    int nb = (N + 1023) >> 10;

    char* ws = (char*)d_ws;
    size_t off = 0;
#define ALLOC(ptr, type, nelem) type* ptr = (type*)(ws + off); off = (off + (size_t)(nelem) * sizeof(type) + 255) & ~(size_t)255
    ALLOC(q_,    float, (size_t)N * CDIM);
    ALLOC(kvs_,  short, (size_t)N * 256);            // interleaved bf16 k|v pairs
    ALLOC(num,   float, (size_t)N * CDIM + 2 * N + N);  // num | den | count -> ONE memset
    float* den_ = num + (size_t)N * CDIM;
    int* count  = (int*)(den_ + 2 * N);
    ALLOC(cur,    int,  N);
    ALLOC(bsum,   int,  nb + 64);
    ALLOC(ed_s,   int4, (size_t)E);
    ALLOC(Wt,     short, 4 * 16384);
    ALLOC(Wet,    short, 16384);
#undef ALLOC

    // single zero region: num | den | count (ws is poisoned before each timed call)
    hipMemsetAsync(num, 0, ((size_t)N * CDIM + 3 * N) * sizeof(float), stream);

    int histB = (E + 255) / 256;
    int PB = (N + 63) / 64;
    prep_kernel<<<WCONV_BLOCKS + histB, 256, 0, stream>>>(ei, E, count,
                                                          Wq, Wk, Wv, Wskip, We, Wt, Wet);
    scan1_kernel<<<nb, 1024, 0, stream>>>(count, N, cur, bsum);
    scan2_kernel<<<1, 64, 0, stream>>>(bsum, nb);
    sp_kernel<<<PB + histB, 256, 0, stream>>>(x, Wt, bq, bk, bv, bskip,
                                              q_, (unsigned int*)kvs_, out, N, PB,
                                              ei, E, tarr, last_up, cur, bsum, ed_s);
    edge_kernel<<<(E + 63) / 64, 256, 0, stream>>>(ed_s, msg, time_w, time_b, Wet,
                                                   q_, (const uint2*)kvs_, num, den_, E);
    norm_kernel<<<(N * 32 + 255) / 256, 256, 0, stream>>>(num, den_, out, N);
}